// Round 9
// baseline (40.421 us; speedup 1.0000x reference)
//
#include <hip/hip_runtime.h>
#include <hip/hip_bf16.h>
#include <math.h>

#define BATCH    4
#define NPTS     8192
#define NSIDE    (BATCH * NPTS)     // 32768 points per side
#define NMINS    (2 * NSIDE)        // 65536 per-query mins
#define THREADS  256
#define RTHREADS 1024
#define INF_BITS 0x7F800000u

// ws layout: [0, 2MB) FB records (2 sides x 32768 x 16 bf16 = 32B); [2MB, 2.25MB) uint mins
#define WS_MIN_OFF (2ull * NSIDE * 32)

typedef __attribute__((ext_vector_type(8)))  short s16x8;   // 8 bf16 = 4 VGPR (MFMA A/B frag)
typedef __attribute__((ext_vector_type(16))) float f32x16;  // MFMA C/D frag

__device__ __forceinline__ short bfbits(float x) {
    union { __hip_bfloat16 b; unsigned short u; } cv;
    cv.b = __float2bfloat16(x);
    return (short)cv.u;
}
__device__ __forceinline__ float bfval(float x) {   // round-to-bf16, back to float
    return __bfloat162float(__float2bfloat16(x));
}

// Slot plan (K=16), P = sum_k FA_k(q) * FB_k(c) = -2 q.c + rq + rc  (validated R7/R8, absmax 0):
//  k0..3 : x: FA=(mxh,mxh,mxl,mxl)  FB=(xh,xl,xh,xl)   (m = -2x, hi/lo bf16 split)
//  k4..7 : y;  k8..11: z
//  k12,13: FA=(rqh,rql) FB=(1,1);  k14,15: FA=(1,1) FB=(rch,rcl)

__global__ __launch_bounds__(THREADS) void chamfer_pre(const float* __restrict__ preds,
                                                       const float* __restrict__ gts,
                                                       s16x8* __restrict__ FBv,
                                                       unsigned int* __restrict__ wsmin) {
    int i = blockIdx.x * THREADS + threadIdx.x;    // 0..65535
    int side = i >> 15;                            // 0: preds, 1: gts
    int n = i & (NSIDE - 1);
    const float* src = side ? gts : preds;
    float x = src[3*n], y = src[3*n+1], z = src[3*n+2];
    float rq = fmaf(x, x, fmaf(y, y, z*z));
    float xh = bfval(x), yh = bfval(y), zh = bfval(z), rh = bfval(rq);
    const short one = (short)0x3F80;
    s16x8 lo, hi;
    lo[0] = bfbits(xh);     lo[1] = bfbits(x - xh);
    lo[2] = lo[0];          lo[3] = lo[1];
    lo[4] = bfbits(yh);     lo[5] = bfbits(y - yh);
    lo[6] = lo[4];          lo[7] = lo[5];
    hi[0] = bfbits(zh);     hi[1] = bfbits(z - zh);
    hi[2] = hi[0];          hi[3] = hi[1];
    hi[4] = one;            hi[5] = one;
    hi[6] = bfbits(rh);     hi[7] = bfbits(rq - rh);
    FBv[2*(size_t)i]     = lo;
    FBv[2*(size_t)i + 1] = hi;
    wsmin[i] = INF_BITS;
}

// A-frag builder for one query row (strip) — identical math to R7/R8.
__device__ __forceinline__ s16x8 make_afrag(const float* __restrict__ Q, int row, int h) {
    const short one = (short)0x3F80;
    float x = Q[3*row], y = Q[3*row+1], z = Q[3*row+2];
    float rq = fmaf(x, x, fmaf(y, y, z*z));
    float xh = bfval(x), yh = bfval(y), zh = bfval(z), rh = bfval(rq);
    s16x8 r;
    if (h == 0) {
        short mh = bfbits(-2.f*xh), ml = bfbits(-2.f*(x - xh));
        short nh = bfbits(-2.f*yh), nl = bfbits(-2.f*(y - yh));
        r[0]=mh; r[1]=mh; r[2]=ml; r[3]=ml;
        r[4]=nh; r[5]=nh; r[6]=nl; r[7]=nl;
    } else {
        short mh = bfbits(-2.f*zh), ml = bfbits(-2.f*(z - zh));
        r[0]=mh; r[1]=mh; r[2]=ml; r[3]=ml;
        r[4]=bfbits(rh); r[5]=bfbits(rq - rh); r[6]=one; r[7]=one;
    }
    return r;
}

// Main: wave = 4 strips x 32 rows (128 rows), cols direct from global; no LDS, no barriers.
__global__ __launch_bounds__(THREADS, 3) void chamfer_mfma(const float* __restrict__ preds,
                                                           const float* __restrict__ gts,
                                                           const s16x8* __restrict__ FBv,
                                                           unsigned int* __restrict__ wsmin) {
    const int rb  = blockIdx.x;        // 0..15 row-block (512 rows)
    const int cq  = blockIdx.y;        // 0..3 col quarter (2048 cols)
    const int dbz = blockIdx.z;        // dir*BATCH + b
    const int dir = dbz >> 2, b = dbz & 3;

    const int t = threadIdx.x, lane = t & 63, wid = t >> 6;
    const int li = lane & 31, h = lane >> 5;   // h: k-half

    const float* __restrict__ Q = (dir ? gts : preds) + (size_t)b * NPTS * 3;
    // candidates: dir=0 -> gts records (side 1); dir=1 -> preds (side 0)
    const s16x8* __restrict__ FBb =
        FBv + 2ull * (((size_t)(dir ^ 1) * BATCH + b) * NPTS + (size_t)cq * 2048);

    // ---- A-frags: 4 strips of 32 rows ----
    const int row0 = rb * 512 + wid * 128 + li;
    const s16x8 a0 = make_afrag(Q, row0,      h);
    const s16x8 a1 = make_afrag(Q, row0 + 32, h);
    const s16x8 a2 = make_afrag(Q, row0 + 64, h);
    const s16x8 a3 = make_afrag(Q, row0 + 96, h);

    // B-frag per lane: lane reads unit 2*li + h of each 32-col tile (64 units/tile).
    const s16x8* __restrict__ Bp = FBb + 2*li + h;

    f32x16 zero = {};
    float rmin0[16], rmin1[16], rmin2[16], rmin3[16];
    #pragma unroll
    for (int r = 0; r < 16; ++r) {
        rmin0[r] = INFINITY; rmin1[r] = INFINITY;
        rmin2[r] = INFINITY; rmin3[r] = INFINITY;
    }

    // 2048 cols = 32 jp x 2 col-tiles; 1-deep prefetch, wrap-clamped (no branch)
    s16x8 nb0 = Bp[0], nb1 = Bp[64];
    #pragma unroll 1
    for (int jp = 0; jp < 32; ++jp) {
        const s16x8 b0 = nb0, b1 = nb1;
        const int nj = (jp + 1) & 31;              // wrap: always in-bounds, no branch
        nb0 = Bp[(size_t)nj * 128];
        nb1 = Bp[(size_t)nj * 128 + 64];
        {   // strip 0: fold immediately -> <=2 D-frags live at any time
            f32x16 d0 = __builtin_amdgcn_mfma_f32_32x32x16_bf16(a0, b0, zero, 0, 0, 0);
            f32x16 d1 = __builtin_amdgcn_mfma_f32_32x32x16_bf16(a0, b1, zero, 0, 0, 0);
            #pragma unroll
            for (int r = 0; r < 16; ++r) rmin0[r] = fminf(fminf(rmin0[r], d0[r]), d1[r]);  // v_min3
        }
        {   // strip 1
            f32x16 d0 = __builtin_amdgcn_mfma_f32_32x32x16_bf16(a1, b0, zero, 0, 0, 0);
            f32x16 d1 = __builtin_amdgcn_mfma_f32_32x32x16_bf16(a1, b1, zero, 0, 0, 0);
            #pragma unroll
            for (int r = 0; r < 16; ++r) rmin1[r] = fminf(fminf(rmin1[r], d0[r]), d1[r]);
        }
        {   // strip 2
            f32x16 d0 = __builtin_amdgcn_mfma_f32_32x32x16_bf16(a2, b0, zero, 0, 0, 0);
            f32x16 d1 = __builtin_amdgcn_mfma_f32_32x32x16_bf16(a2, b1, zero, 0, 0, 0);
            #pragma unroll
            for (int r = 0; r < 16; ++r) rmin2[r] = fminf(fminf(rmin2[r], d0[r]), d1[r]);
        }
        {   // strip 3
            f32x16 d0 = __builtin_amdgcn_mfma_f32_32x32x16_bf16(a3, b0, zero, 0, 0, 0);
            f32x16 d1 = __builtin_amdgcn_mfma_f32_32x32x16_bf16(a3, b1, zero, 0, 0, 0);
            #pragma unroll
            for (int r = 0; r < 16; ++r) rmin3[r] = fminf(fminf(rmin3[r], d0[r]), d1[r]);
        }
    }

    // ---- epilogue: min over 32 cols (xor<=16 keeps k-half), atomicMin per row ----
    unsigned int* __restrict__ wbase = wsmin + ((size_t)dir * BATCH + b) * NPTS;
    #pragma unroll
    for (int r = 0; r < 16; ++r) {
        float m0 = rmin0[r], m1 = rmin1[r], m2 = rmin2[r], m3 = rmin3[r];
        #pragma unroll
        for (int off = 1; off <= 16; off <<= 1) {
            m0 = fminf(m0, __shfl_xor(m0, off, 64));
            m1 = fminf(m1, __shfl_xor(m1, off, 64));
            m2 = fminf(m2, __shfl_xor(m2, off, 64));
            m3 = fminf(m3, __shfl_xor(m3, off, 64));
        }
        if (li == 0) {
            int rowin = (r & 3) + 8 * (r >> 2) + 4 * h;   // C/D row map (validated R7/R8)
            int rbase = rb * 512 + wid * 128 + rowin;
            atomicMin(&wbase[rbase     ], __float_as_uint(fmaxf(m0, 0.f)));
            atomicMin(&wbase[rbase + 32], __float_as_uint(fmaxf(m1, 0.f)));
            atomicMin(&wbase[rbase + 64], __float_as_uint(fmaxf(m2, 0.f)));
            atomicMin(&wbase[rbase + 96], __float_as_uint(fmaxf(m3, 0.f)));
        }
    }
}

__global__ __launch_bounds__(RTHREADS) void chamfer_reduce(const unsigned int* __restrict__ wsmin,
                                                           float* __restrict__ out) {
    const float4* __restrict__ v = (const float4*)wsmin;  // bits are valid floats (>=0)
    float s = 0.0f;
    int i = threadIdx.x;
    #pragma unroll
    for (int it = 0; it < NMINS / 4 / RTHREADS; ++it, i += RTHREADS) {
        float4 a = v[i];
        s += (a.x + a.y) + (a.z + a.w);
    }
    for (int off = 32; off; off >>= 1) s += __shfl_down(s, off, 64);
    __shared__ float sm[RTHREADS / 64];
    if ((threadIdx.x & 63) == 0) sm[threadIdx.x >> 6] = s;
    __syncthreads();
    if (threadIdx.x == 0) {
        float tt = 0.0f;
        #pragma unroll
        for (int w = 0; w < RTHREADS / 64; ++w) tt += sm[w];
        out[0] = tt / (float)NPTS;   // sum(mins1)/M + sum(mins2)/N, M=N=NPTS
    }
}

extern "C" void kernel_launch(void* const* d_in, const int* in_sizes, int n_in,
                              void* d_out, int out_size, void* d_ws, size_t ws_size,
                              hipStream_t stream) {
    const float* preds = (const float*)d_in[0];
    const float* gts   = (const float*)d_in[1];
    float* out = (float*)d_out;
    s16x8* FBv = (s16x8*)d_ws;
    unsigned int* wsmin = (unsigned int*)((char*)d_ws + WS_MIN_OFF);

    chamfer_pre<<<NMINS / THREADS, THREADS, 0, stream>>>(preds, gts, FBv, wsmin);

    dim3 grid(16, 4, 2 * BATCH);   // row-blocks(512 rows) x col-quarters x (dir*BATCH+b)
    chamfer_mfma<<<grid, THREADS, 0, stream>>>(preds, gts, FBv, wsmin);

    chamfer_reduce<<<1, RTHREADS, 0, stream>>>(wsmin, out);
}

// Round 10
// 37.067 us; speedup vs baseline: 1.0905x; 1.0905x over previous
//
#include <hip/hip_runtime.h>
#include <hip/hip_bf16.h>
#include <math.h>

#define BATCH    4
#define NPTS     8192
#define NSIDE    (BATCH * NPTS)     // 32768 points per side
#define NMINS    (2 * NSIDE)        // 65536 per-query mins
#define THREADS  256
#define RTHREADS 1024
#define INF_BITS 0x7F800000u

// ws layout: [0, 2MB) FB records (2 sides x 32768 x 16 bf16 = 32B); [2MB, 2.25MB) uint mins
#define WS_MIN_OFF (2ull * NSIDE * 32)

typedef __attribute__((ext_vector_type(8)))  short s16x8;   // 8 bf16 = 4 VGPR (MFMA A/B frag)
typedef __attribute__((ext_vector_type(16))) float f32x16;  // MFMA C/D frag

__device__ __forceinline__ short bfbits(float x) {
    union { __hip_bfloat16 b; unsigned short u; } cv;
    cv.b = __float2bfloat16(x);
    return (short)cv.u;
}
__device__ __forceinline__ float bfval(float x) {   // round-to-bf16, back to float
    return __bfloat162float(__float2bfloat16(x));
}

// Slot plan (K=16), P = sum_k FA_k(q) * FB_k(c) = -2 q.c + rq + rc  (validated R7/R8/R9, absmax 0):
//  k0..3 : x: FA=(mxh,mxh,mxl,mxl)  FB=(xh,xl,xh,xl)   (m = -2x, hi/lo bf16 split)
//  k4..7 : y;  k8..11: z
//  k12,13: FA=(rqh,rql) FB=(1,1);  k14,15: FA=(1,1) FB=(rch,rcl)

__global__ __launch_bounds__(THREADS) void chamfer_pre(const float* __restrict__ preds,
                                                       const float* __restrict__ gts,
                                                       s16x8* __restrict__ FBv,
                                                       unsigned int* __restrict__ wsmin) {
    int i = blockIdx.x * THREADS + threadIdx.x;    // 0..65535
    int side = i >> 15;                            // 0: preds, 1: gts
    int n = i & (NSIDE - 1);
    const float* src = side ? gts : preds;
    float x = src[3*n], y = src[3*n+1], z = src[3*n+2];
    float rq = fmaf(x, x, fmaf(y, y, z*z));
    float xh = bfval(x), yh = bfval(y), zh = bfval(z), rh = bfval(rq);
    const short one = (short)0x3F80;
    s16x8 lo, hi;
    lo[0] = bfbits(xh);     lo[1] = bfbits(x - xh);
    lo[2] = lo[0];          lo[3] = lo[1];
    lo[4] = bfbits(yh);     lo[5] = bfbits(y - yh);
    lo[6] = lo[4];          lo[7] = lo[5];
    hi[0] = bfbits(zh);     hi[1] = bfbits(z - zh);
    hi[2] = hi[0];          hi[3] = hi[1];
    hi[4] = one;            hi[5] = one;
    hi[6] = bfbits(rh);     hi[7] = bfbits(rq - rh);
    FBv[2*(size_t)i]     = lo;
    FBv[2*(size_t)i + 1] = hi;
    wsmin[i] = INF_BITS;
}

// A-frag builder for one query row (strip) — identical math to R7/R8/R9.
__device__ __forceinline__ s16x8 make_afrag(const float* __restrict__ Q, int row, int h) {
    const short one = (short)0x3F80;
    float x = Q[3*row], y = Q[3*row+1], z = Q[3*row+2];
    float rq = fmaf(x, x, fmaf(y, y, z*z));
    float xh = bfval(x), yh = bfval(y), zh = bfval(z), rh = bfval(rq);
    s16x8 r;
    if (h == 0) {
        short mh = bfbits(-2.f*xh), ml = bfbits(-2.f*(x - xh));
        short nh = bfbits(-2.f*yh), nl = bfbits(-2.f*(y - yh));
        r[0]=mh; r[1]=mh; r[2]=ml; r[3]=ml;
        r[4]=nh; r[5]=nh; r[6]=nl; r[7]=nl;
    } else {
        short mh = bfbits(-2.f*zh), ml = bfbits(-2.f*(z - zh));
        r[0]=mh; r[1]=mh; r[2]=ml; r[3]=ml;
        r[4]=bfbits(rh); r[5]=bfbits(rq - rh); r[6]=one; r[7]=one;
    }
    return r;
}

// Main: wave = 2 strips x 32 rows; B direct from global (L2-resident), 2-deep prefetch;
// no LDS, no barriers; setprio(1) around MFMA clusters (waves at random phases -> arbitration pays).
__global__ __launch_bounds__(THREADS, 4) void chamfer_mfma(const float* __restrict__ preds,
                                                           const float* __restrict__ gts,
                                                           const s16x8* __restrict__ FBv,
                                                           unsigned int* __restrict__ wsmin) {
    const int rb  = blockIdx.x;        // 0..31 row-block (256 rows)
    const int cq  = blockIdx.y;        // 0..3 col quarter (2048 cols)
    const int dbz = blockIdx.z;        // dir*BATCH + b
    const int dir = dbz >> 2, b = dbz & 3;

    const int t = threadIdx.x, lane = t & 63, wid = t >> 6;
    const int li = lane & 31, h = lane >> 5;   // h: k-half

    const float* __restrict__ Q = (dir ? gts : preds) + (size_t)b * NPTS * 3;
    // candidates: dir=0 -> gts records (side 1); dir=1 -> preds (side 0)
    const s16x8* __restrict__ FBb =
        FBv + 2ull * (((size_t)(dir ^ 1) * BATCH + b) * NPTS + (size_t)cq * 2048);

    // ---- A-frags: 2 strips of 32 rows ----
    const int row0 = rb * 256 + wid * 64 + li;
    const s16x8 a0 = make_afrag(Q, row0,      h);
    const s16x8 a1 = make_afrag(Q, row0 + 32, h);

    // B-frag per lane: lane reads unit 2*li + h of each 32-col tile (64 units/tile).
    const s16x8* __restrict__ Bp = FBb + 2*li + h;

    f32x16 zero = {};
    float rmin0[16], rmin1[16];
    #pragma unroll
    for (int r = 0; r < 16; ++r) { rmin0[r] = INFINITY; rmin1[r] = INFINITY; }

    // 2048 cols = 32 jp x 2 col-tiles; 2-deep prefetch, static names only (rule #20),
    // wrap-clamped indices (no branch, always in-bounds).
    s16x8 c0 = Bp[0],   c1 = Bp[64];     // tiles of jp
    s16x8 n0 = Bp[128], n1 = Bp[192];    // tiles of jp+1

    #pragma unroll 1
    for (int jp = 0; jp < 32; jp += 2) {
        const int j2 = (jp + 2) & 31, j3 = (jp + 3) & 31;

        // ---- sub-iter A: compute on c0,c1; prefetch jp+2 ----
        s16x8 f0 = Bp[(size_t)j2 * 128], f1 = Bp[(size_t)j2 * 128 + 64];
        {
            __builtin_amdgcn_s_setprio(1);
            f32x16 d0 = __builtin_amdgcn_mfma_f32_32x32x16_bf16(a0, c0, zero, 0, 0, 0);
            f32x16 d1 = __builtin_amdgcn_mfma_f32_32x32x16_bf16(a0, c1, zero, 0, 0, 0);
            __builtin_amdgcn_s_setprio(0);
            #pragma unroll
            for (int r = 0; r < 16; ++r) rmin0[r] = fminf(fminf(rmin0[r], d0[r]), d1[r]);  // v_min3
        }
        {
            __builtin_amdgcn_s_setprio(1);
            f32x16 d0 = __builtin_amdgcn_mfma_f32_32x32x16_bf16(a1, c0, zero, 0, 0, 0);
            f32x16 d1 = __builtin_amdgcn_mfma_f32_32x32x16_bf16(a1, c1, zero, 0, 0, 0);
            __builtin_amdgcn_s_setprio(0);
            #pragma unroll
            for (int r = 0; r < 16; ++r) rmin1[r] = fminf(fminf(rmin1[r], d0[r]), d1[r]);
        }

        // ---- sub-iter B: compute on n0,n1; prefetch jp+3 ----
        s16x8 g0 = Bp[(size_t)j3 * 128], g1 = Bp[(size_t)j3 * 128 + 64];
        {
            __builtin_amdgcn_s_setprio(1);
            f32x16 d0 = __builtin_amdgcn_mfma_f32_32x32x16_bf16(a0, n0, zero, 0, 0, 0);
            f32x16 d1 = __builtin_amdgcn_mfma_f32_32x32x16_bf16(a0, n1, zero, 0, 0, 0);
            __builtin_amdgcn_s_setprio(0);
            #pragma unroll
            for (int r = 0; r < 16; ++r) rmin0[r] = fminf(fminf(rmin0[r], d0[r]), d1[r]);
        }
        {
            __builtin_amdgcn_s_setprio(1);
            f32x16 d0 = __builtin_amdgcn_mfma_f32_32x32x16_bf16(a1, n0, zero, 0, 0, 0);
            f32x16 d1 = __builtin_amdgcn_mfma_f32_32x32x16_bf16(a1, n1, zero, 0, 0, 0);
            __builtin_amdgcn_s_setprio(0);
            #pragma unroll
            for (int r = 0; r < 16; ++r) rmin1[r] = fminf(fminf(rmin1[r], d0[r]), d1[r]);
        }

        c0 = f0; c1 = f1; n0 = g0; n1 = g1;    // rotate pipeline (reg moves)
    }

    // ---- epilogue: min over 32 cols (xor<=16 keeps k-half), atomicMin per row ----
    unsigned int* __restrict__ wbase = wsmin + ((size_t)dir * BATCH + b) * NPTS;
    #pragma unroll
    for (int r = 0; r < 16; ++r) {
        float m0 = rmin0[r], m1 = rmin1[r];
        #pragma unroll
        for (int off = 1; off <= 16; off <<= 1) {
            m0 = fminf(m0, __shfl_xor(m0, off, 64));
            m1 = fminf(m1, __shfl_xor(m1, off, 64));
        }
        if (li == 0) {
            int rowin = (r & 3) + 8 * (r >> 2) + 4 * h;   // C/D row map (validated R7/R8/R9)
            int rbase = rb * 256 + wid * 64 + rowin;
            atomicMin(&wbase[rbase     ], __float_as_uint(fmaxf(m0, 0.f)));
            atomicMin(&wbase[rbase + 32], __float_as_uint(fmaxf(m1, 0.f)));
        }
    }
}

__global__ __launch_bounds__(RTHREADS) void chamfer_reduce(const unsigned int* __restrict__ wsmin,
                                                           float* __restrict__ out) {
    const float4* __restrict__ v = (const float4*)wsmin;  // bits are valid floats (>=0)
    float s = 0.0f;
    int i = threadIdx.x;
    #pragma unroll
    for (int it = 0; it < NMINS / 4 / RTHREADS; ++it, i += RTHREADS) {
        float4 a = v[i];
        s += (a.x + a.y) + (a.z + a.w);
    }
    for (int off = 32; off; off >>= 1) s += __shfl_down(s, off, 64);
    __shared__ float sm[RTHREADS / 64];
    if ((threadIdx.x & 63) == 0) sm[threadIdx.x >> 6] = s;
    __syncthreads();
    if (threadIdx.x == 0) {
        float tt = 0.0f;
        #pragma unroll
        for (int w = 0; w < RTHREADS / 64; ++w) tt += sm[w];
        out[0] = tt / (float)NPTS;   // sum(mins1)/M + sum(mins2)/N, M=N=NPTS
    }
}

extern "C" void kernel_launch(void* const* d_in, const int* in_sizes, int n_in,
                              void* d_out, int out_size, void* d_ws, size_t ws_size,
                              hipStream_t stream) {
    const float* preds = (const float*)d_in[0];
    const float* gts   = (const float*)d_in[1];
    float* out = (float*)d_out;
    s16x8* FBv = (s16x8*)d_ws;
    unsigned int* wsmin = (unsigned int*)((char*)d_ws + WS_MIN_OFF);

    chamfer_pre<<<NMINS / THREADS, THREADS, 0, stream>>>(preds, gts, FBv, wsmin);

    dim3 grid(32, 4, 2 * BATCH);   // row-blocks(256 rows) x col-quarters x (dir*BATCH+b)
    chamfer_mfma<<<grid, THREADS, 0, stream>>>(preds, gts, FBv, wsmin);

    chamfer_reduce<<<1, RTHREADS, 0, stream>>>(wsmin, out);
}